// Round 7
// baseline (174.161 us; speedup 1.0000x reference)
//
#include <hip/hip_runtime.h>
#include <hip/hip_bf16.h>

typedef unsigned short u16;
typedef __attribute__((ext_vector_type(8))) short short8;
typedef __attribute__((ext_vector_type(16))) float f32x16;

#define MFMA(A,B,C) __builtin_amdgcn_mfma_f32_32x32x16_bf16(A,B,C,0,0,0)
#define NEG_INF -1e30f

__device__ __forceinline__ unsigned cvtpk_bf16(float a, float b) {
    unsigned r;
    asm("v_cvt_pk_bf16_f32 %0, %1, %2" : "=v"(r) : "v"(a), "v"(b));
    return r;
}
__device__ __forceinline__ void permswap(unsigned &a, unsigned &b) {
    auto r = __builtin_amdgcn_permlane32_swap(a, b, false, false);
    a = r[0]; b = r[1];
}
union W4u { unsigned u[4]; short8 v; };
__device__ __forceinline__ short8 mk8(unsigned a, unsigned b, unsigned c, unsigned d) {
    W4u w; w.u[0] = a; w.u[1] = b; w.u[2] = c; w.u[3] = d; return w.v;
}
__device__ __forceinline__ void split_words(float p0, float p1, unsigned &wh, unsigned &wl) {
    wh = cvtpk_bf16(p0, p1);
    float h0 = __uint_as_float(wh << 16);
    float h1 = __uint_as_float(wh & 0xffff0000u);
    wl = cvtpk_bf16(p0 - h0, p1 - h1);
}
__device__ __forceinline__ void split_store(float v, u16* ph, u16* pl) {
    __hip_bfloat16 h = __float2bfloat16(v);
    float hf = __bfloat162float(h);
    __hip_bfloat16 l = __float2bfloat16(v - hf);
    *ph = *(u16*)&h;
    *pl = *(u16*)&l;
}
__device__ __forceinline__ short8 ld8(const u16* p) { return *(const short8*)p; }

// chunks (CH=1<<lc 64-key tiles each) in 64-row q-strips [0, qs) of one batch:
// cb64(qs) = sum_{j=1..qs} ceil(j/CH)
__device__ __forceinline__ int cb64(int qs, int lc) {
    int u = qs >> lc, r = qs - (u << lc);
    return (((u * (u + 1)) >> 1) << lc) + r * (u + 1);
}

// fragment-linear index for Q/K: row grow (global across b*4096+t), col 0..63
__device__ __forceinline__ size_t qk_idx(int grow, int col) {
    return (size_t)(grow >> 5) * 2048 + (col >> 4) * 512 + (grow & 31) * 16
         + ((col >> 3) & 1) * 8 + (col & 7);
}

// pack one strip's P (c_sub0, c_sub1 f32x16) into 4 hi + 4 lo B-fragments
__device__ __forceinline__ void pack_strip(const f32x16 &ca, const f32x16 &cb,
                                           short8 *pbh, short8 *pbl) {
    unsigned wAh, wAl, wBh, wBl, wCh, wCl, wDh, wDl;
    split_words(ca[0], ca[1], wAh, wAl);   split_words(ca[2], ca[3], wBh, wBl);
    split_words(ca[4], ca[5], wCh, wCl);   split_words(ca[6], ca[7], wDh, wDl);
    permswap(wAh, wCh); permswap(wBh, wDh); permswap(wAl, wCl); permswap(wBl, wDl);
    pbh[0] = mk8(wAh, wBh, wCh, wDh); pbl[0] = mk8(wAl, wBl, wCl, wDl);
    split_words(ca[8], ca[9], wAh, wAl);   split_words(ca[10], ca[11], wBh, wBl);
    split_words(ca[12], ca[13], wCh, wCl); split_words(ca[14], ca[15], wDh, wDl);
    permswap(wAh, wCh); permswap(wBh, wDh); permswap(wAl, wCl); permswap(wBl, wDl);
    pbh[1] = mk8(wAh, wBh, wCh, wDh); pbl[1] = mk8(wAl, wBl, wCl, wDl);
    split_words(cb[0], cb[1], wAh, wAl);   split_words(cb[2], cb[3], wBh, wBl);
    split_words(cb[4], cb[5], wCh, wCl);   split_words(cb[6], cb[7], wDh, wDl);
    permswap(wAh, wCh); permswap(wBh, wDh); permswap(wAl, wCl); permswap(wBl, wDl);
    pbh[2] = mk8(wAh, wBh, wCh, wDh); pbl[2] = mk8(wAl, wBl, wCl, wDl);
    split_words(cb[8], cb[9], wAh, wAl);   split_words(cb[10], cb[11], wBh, wBl);
    split_words(cb[12], cb[13], wCh, wCl); split_words(cb[14], cb[15], wDh, wDl);
    permswap(wAh, wCh); permswap(wBh, wDh); permswap(wAl, wCl); permswap(wBl, wDl);
    pbh[3] = mk8(wAh, wBh, wCh, wDh); pbl[3] = mk8(wAl, wBl, wCl, wDl);
}

// ---------------------------------------------------------------------------
// Weights (fp32 [512][64]) -> fragment-linear hi/lo bf16 planes.
// Staged in LDS, coalesced 16B stores.
// ---------------------------------------------------------------------------
__global__ void convw_kernel(
    const float* __restrict__ Wq, const float* __restrict__ Wk, const float* __restrict__ Wv,
    const float* __restrict__ Wqs, const float* __restrict__ Wks, const float* __restrict__ Wvs,
    u16* __restrict__ wbase)
{
    const int z = blockIdx.y;      // 0..5
    const int tile = blockIdx.x;   // 0..7 (64-d chunks)
    const float* W = (z == 0) ? Wq : (z == 1) ? Wk : (z == 2) ? Wv
                   : (z == 3) ? Wqs : (z == 4) ? Wks : Wvs;
    u16* oh = wbase + (size_t)z * 65536;
    u16* ol = oh + 32768;
    __shared__ float Xs[64][65];
    __shared__ u16 stg[8192];
    const int tid = threadIdx.x;
    const int d0 = tile * 64;
    #pragma unroll
    for (int k = 0; k < 16; ++k) {
        int idx = tid + k * 256;
        int d = idx >> 6, c = idx & 63;
        Xs[d][c] = W[(size_t)(d0 + d) * 64 + c];
    }
    __syncthreads();
    // local fragment-linear index == odx (bit-exact): [11:10]=sl [9:4]=r [3]=hi8 [2:0]=j
    #pragma unroll
    for (int k = 0; k < 16; ++k) {
        int odx = tid + k * 256;
        int j = odx & 7, hi8 = (odx >> 3) & 1, r = (odx >> 4) & 63, sl = odx >> 10;
        split_store(Xs[sl * 16 + hi8 * 8 + j][r], &stg[odx], &stg[4096 + odx]);
    }
    __syncthreads();
    #pragma unroll
    for (int rep = 0; rep < 2; ++rep) {
        int i = (tid * 2 + rep) * 8;
        *(short8*)&oh[(size_t)tile * 4096 + i] = *(const short8*)&stg[i];
        *(short8*)&ol[(size_t)tile * 4096 + i] = *(const short8*)&stg[4096 + i];
    }
}

// ---------------------------------------------------------------------------
// QKV projection. 2-wave blocks (K-split), LDS cross-wave reduce, then LDS
// staging + coalesced 16B stores (edge rows predicated at 16B granularity).
// Blocks 0..511: mid weights; 512..513: the 64 edge rows with _s weights.
// ---------------------------------------------------------------------------
__global__ __launch_bounds__(128, 2) void proj_kernel(
    const float* __restrict__ x, const u16* __restrict__ wbase,
    u16* __restrict__ qh, u16* __restrict__ ql,
    u16* __restrict__ kh, u16* __restrict__ kl,
    u16* __restrict__ vth, u16* __restrict__ vtl)
{
    __shared__ __align__(16) char smraw[24576];
    float (*red)[16][64] = (float (*)[16][64])smraw;   // [6][16][64]
    u16* stg = (u16*)smraw;                            // 12288 u16

    const int bid = blockIdx.x;
    const bool edge = (bid >= 512);
    int sidx;
    if (!edge) { int xcd = bid & 7; sidx = (xcd >> 1) * 128 + (xcd & 1) * 64 + (bid >> 3); }
    else sidx = bid;
    const int w = threadIdx.x >> 6;
    const int lane = threadIdx.x & 63;
    const int l31 = lane & 31, hi = lane >> 5;

    const u16* wb = wbase + (edge ? (size_t)3 * 65536 : 0);
    const u16* wqh_ = wb;                 const u16* wql_ = wb + 32768;
    const u16* wkh_ = wb + 65536;         const u16* wkl_ = wb + 65536 + 32768;
    const u16* wvh_ = wb + 2 * 65536;     const u16* wvl_ = wb + 2 * 65536 + 32768;

    int growA;
    if (!edge) growA = sidx * 32 + l31;
    else {
        int e = sidx - 512, rb = l31 >> 4, i = l31 & 15;
        growA = (2 * e + rb) * 4096 + (i < 8 ? i : 4080 + i);
    }
    const float* xrow = x + (size_t)growA * 512;

    f32x16 aq[2] = {{}, {}}, ak[2] = {{}, {}}, av[2] = {{}, {}};
    const int s0 = w * 16;
    #pragma unroll 2
    for (int si = 0; si < 16; ++si) {
        const int s = s0 + si;
        const int d0 = s * 16 + 8 * hi;
        float4 xa = *(const float4*)(xrow + d0);
        float4 xb = *(const float4*)(xrow + d0 + 4);
        unsigned xh_[4], xl_[4];
        split_words(xa.x, xa.y, xh_[0], xl_[0]);
        split_words(xa.z, xa.w, xh_[1], xl_[1]);
        split_words(xb.x, xb.y, xh_[2], xl_[2]);
        split_words(xb.z, xb.w, xh_[3], xl_[3]);
        short8 xhf = mk8(xh_[0], xh_[1], xh_[2], xh_[3]);
        short8 xlf = mk8(xl_[0], xl_[1], xl_[2], xl_[3]);
        #pragma unroll
        for (int half = 0; half < 2; ++half) {
            size_t wof = (size_t)s * 1024 + (half * 32 + l31) * 16 + hi * 8;
            short8 qH = ld8(wqh_ + wof), qL = ld8(wql_ + wof);
            short8 kH = ld8(wkh_ + wof), kL = ld8(wkl_ + wof);
            short8 vH = ld8(wvh_ + wof), vL = ld8(wvl_ + wof);
            aq[half] = MFMA(xhf, qH, aq[half]);
            aq[half] = MFMA(xhf, qL, aq[half]);
            aq[half] = MFMA(xlf, qH, aq[half]);
            ak[half] = MFMA(xhf, kH, ak[half]);
            ak[half] = MFMA(xhf, kL, ak[half]);
            ak[half] = MFMA(xlf, kH, ak[half]);
            av[half] = MFMA(vH, xhf, av[half]);
            av[half] = MFMA(vL, xhf, av[half]);
            av[half] = MFMA(vH, xlf, av[half]);
        }
    }
    // publish partials: wave1 -> q,k; wave0 -> v
    if (w == 1) {
        #pragma unroll
        for (int h = 0; h < 2; ++h)
            #pragma unroll
            for (int r = 0; r < 16; ++r) {
                red[h][r][lane] = aq[h][r];
                red[2 + h][r][lane] = ak[h][r];
            }
    } else {
        #pragma unroll
        for (int h = 0; h < 2; ++h)
            #pragma unroll
            for (int r = 0; r < 16; ++r) red[4 + h][r][lane] = av[h][r];
    }
    __syncthreads();
    // sums into registers
    if (w == 0) {
        #pragma unroll
        for (int h = 0; h < 2; ++h)
            #pragma unroll
            for (int r = 0; r < 16; ++r) {
                aq[h][r] += red[h][r][lane];
                ak[h][r] += red[2 + h][r][lane];
            }
    } else {
        #pragma unroll
        for (int h = 0; h < 2; ++h)
            #pragma unroll
            for (int r = 0; r < 16; ++r) av[h][r] += red[4 + h][r][lane];
    }
    __syncthreads();   // red reads done; LDS now reusable as staging

    if (!edge) {
        // stage into fragment-linear LDS regions
        if (w == 0) {
            #pragma unroll
            for (int half = 0; half < 2; ++half)
                #pragma unroll
                for (int r = 0; r < 16; ++r) {
                    const int crow = (r & 3) + 8 * (r >> 2) + 4 * hi;
                    const int col = half * 32 + l31;
                    int loff = (col >> 4) * 512 + crow * 16 + ((col >> 3) & 1) * 8 + (col & 7);
                    split_store(aq[half][r] * 0.125f, &stg[loff], &stg[2048 + loff]);
                    split_store(ak[half][r], &stg[4096 + loff], &stg[6144 + loff]);
                }
        } else {
            #pragma unroll
            for (int half = 0; half < 2; ++half)
                #pragma unroll
                for (int r = 0; r < 16; ++r) {
                    const int crow = (r & 3) + 8 * (r >> 2) + 4 * hi;
                    int lv = half * 1024 + (l31 >> 4) * 512 + crow * 16
                           + ((l31 >> 3) & 1) * 8 + (l31 & 7);
                    split_store(av[half][r], &stg[8192 + lv], &stg[10240 + lv]);
                }
        }
        __syncthreads();
        // coalesced copy-out (both waves, 128 threads)
        const int t128 = threadIdx.x;
        const int sloc = sidx & 127;
        u16* qk0 = qh + (size_t)sidx * 2048;
        u16* qk1 = ql + (size_t)sidx * 2048;
        u16* qk2 = kh + (size_t)sidx * 2048;
        u16* qk3 = kl + (size_t)sidx * 2048;
        #pragma unroll
        for (int rep = 0; rep < 2; ++rep) {
            int i = (t128 * 2 + rep) * 8;            // 0..2040 step 8
            int crow_ = (i >> 4) & 31;
            int tin = sloc * 32 + crow_;
            if (tin >= 8 && tin < 4088) {
                *(short8*)&qk0[i] = *(const short8*)&stg[i];
                *(short8*)&qk1[i] = *(const short8*)&stg[2048 + i];
                *(short8*)&qk2[i] = *(const short8*)&stg[4096 + i];
                *(short8*)&qk3[i] = *(const short8*)&stg[6144 + i];
            }
        }
        // V tile base: global ttile = b*64 + (sloc>>1) == sidx>>1  (R6 bug: had
        // (sidx>>7)*64 + (sidx>>1), double-counting the batch term)
        const size_t Vbase = (size_t)(sidx >> 1) * 4096;
        #pragma unroll
        for (int rep = 0; rep < 2; ++rep) {
            int i = (t128 * 2 + rep) * 8;
            int T = ((i >> 9) & 1) * 16 + ((i >> 3) & 1) * 8;
            int tbase = sloc * 32 + T;
            if (tbase >= 8 && tbase < 4088) {
                size_t go = Vbase + (size_t)(i >> 10) * 2048
                          + (((sidx & 1) << 1) + ((i >> 9) & 1)) * 512 + (i & 511);
                *(short8*)&vth[go] = *(const short8*)&stg[8192 + i];
                *(short8*)&vtl[go] = *(const short8*)&stg[10240 + i];
            }
        }
    } else {
        // edge blocks: direct (scattered) stores — only 2 blocks
        const int bv = growA >> 12, tv = growA & 4095;
        if (w == 0) {
            #pragma unroll
            for (int half = 0; half < 2; ++half)
                #pragma unroll
                for (int r = 0; r < 16; ++r) {
                    const int crow = (r & 3) + 8 * (r >> 2) + 4 * hi;
                    const int col = half * 32 + l31;
                    int e = sidx - 512, rb = crow >> 4, i = crow & 15;
                    int growC = (2 * e + rb) * 4096 + (i < 8 ? i : 4080 + i);
                    size_t qo = qk_idx(growC, col);
                    split_store(aq[half][r] * 0.125f, qh + qo, ql + qo);
                    split_store(ak[half][r], kh + qo, kl + qo);
                }
        } else {
            #pragma unroll
            for (int half = 0; half < 2; ++half)
                #pragma unroll
                for (int r = 0; r < 16; ++r) {
                    const int crow = (r & 3) + 8 * (r >> 2) + 4 * hi;
                    size_t vo = (size_t)(bv * 64 + (tv >> 6)) * 4096 + half * 2048
                              + ((tv & 63) >> 4) * 512 + crow * 16
                              + ((tv >> 3) & 1) * 8 + (tv & 7);
                    split_store(av[half][r], vth + vo, vtl + vo);
                }
        }
    }
}

// ---------------------------------------------------------------------------
// Flash attention: 64 q-rows per wave (2 strips share K/V fragments -> 2x
// arithmetic intensity). Uniform chunks of CH tiles, XCD-affine batches,
// LPT order. K-operand footprint kept to 16 VGPR via split hi/lo passes.
// ---------------------------------------------------------------------------
__global__ __launch_bounds__(64, 2) void flash_kernel(
    const u16* __restrict__ qhB, const u16* __restrict__ qlB,
    const u16* __restrict__ khB, const u16* __restrict__ klB,
    const u16* __restrict__ vthB, const u16* __restrict__ vtlB,
    float* __restrict__ Opart, float* __restrict__ mpart, float* __restrict__ lpart,
    int lc, int G)
{
    const int bid = blockIdx.x;
    const int xcd = bid & 7;
    const int b = xcd >> 1, par = xcd & 1;
    const int rr = bid >> 3;
    const int chunk = (G - 1) - (2 * rr + par);     // heavy chunks first (LPT)
    int qs = 0;
    for (int step = 32; step; step >>= 1) {
        int cand = qs + step;
        if (cand < 64 && cb64(cand, lc) <= chunk) qs = cand;
    }
    const int cloc = chunk - cb64(qs, lc);
    const int nt = qs + 1;
    const int klo = cloc << lc;
    const int lim = klo + (1 << lc);
    const int khi = (nt < lim) ? nt : lim;
    const int lane = threadIdx.x, l31 = lane & 31, hi = lane >> 5;
    const size_t lane_off = (size_t)(l31 * 16 + hi * 8);

    const size_t qb0 = (size_t)(b * 128 + qs * 2) * 2048 + lane_off;
    short8 q0h[4], q0l[4], q1h[4], q1l[4];
    #pragma unroll
    for (int s = 0; s < 4; ++s) {
        q0h[s] = ld8(qhB + qb0 + s * 512);
        q0l[s] = ld8(qlB + qb0 + s * 512);
        q1h[s] = ld8(qhB + qb0 + 2048 + s * 512);
        q1l[s] = ld8(qlB + qb0 + 2048 + s * 512);
    }

    f32x16 o00 = {}, o01 = {}, o10 = {}, o11 = {};
    float m0 = NEG_INF, l0 = 0.f, m1 = NEG_INF, l1 = 0.f;

    for (int kb = klo; kb < khi; ++kb) {
        const bool diag = (kb == qs);
        const size_t kt = (size_t)(b * 128 + kb * 2) * 2048 + lane_off;
        short8 kf[4];
        f32x16 c00 = {}, c01 = {}, c11 = {};
        f32x16 c10;
        #pragma unroll
        for (int r = 0; r < 16; ++r) c10[r] = diag ? NEG_INF : 0.f;

        // sub0 (keys 0..31), hi plane
        #pragma unroll
        for (int s = 0; s < 4; ++s) kf[s] = ld8(khB + kt + s * 512);
        __builtin_amdgcn_s_setprio(1);
        #pragma unroll
        for (int s = 0; s < 4; ++s) {
            c00 = MFMA(kf[s], q0h[s], c00);
            c00 = MFMA(kf[s], q0l[s], c00);
            c01 = MFMA(kf[s], q1h[s], c01);
            c01 = MFMA(kf[s], q1l[s], c01);
        }
        __builtin_amdgcn_s_setprio(0);
        // sub0, lo plane
        #pragma unroll
        for (int s = 0; s < 4; ++s) kf[s] = ld8(klB + kt + s * 512);
        __builtin_amdgcn_s_setprio(1);
        #pragma unroll
        for (int s = 0; s < 4; ++s) {
            c00 = MFMA(kf[s], q0h[s], c00);
            c01 = MFMA(kf[s], q1h[s], c01);
        }
        __builtin_amdgcn_s_setprio(0);
        // sub1 (keys 32..63), hi plane
        #pragma unroll
        for (int s = 0; s < 4; ++s) kf[s] = ld8(khB + kt + 2048 + s * 512);
        __builtin_amdgcn_s_setprio(1);
        if (!diag) {
            #pragma unroll
            for (int s = 0; s < 4; ++s) {
                c10 = MFMA(kf[s], q0h[s], c10);
                c10 = MFMA(kf[s], q0l[s], c10);
            }
        }
        #pragma unroll
        for (int s = 0; s < 4; ++s) {
            c11 = MFMA(kf[s], q1h[s], c11);
            c11 = MFMA(kf[s], q1l[s], c11);
        }
        __builtin_amdgcn_s_setprio(0);
        // sub1, lo plane
        #pragma unroll
        for (int s = 0; s < 4; ++s) kf[s] = ld8(klB + kt + 2048 + s * 512);
        __builtin_amdgcn_s_setprio(1);
        if (!diag) {
            #pragma unroll
            for (int s = 0; s < 4; ++s) c10 = MFMA(kf[s], q0h[s], c10);
        }
        #pragma unroll
        for (int s = 0; s < 4; ++s) c11 = MFMA(kf[s], q1h[s], c11);
        __builtin_amdgcn_s_setprio(0);

        if (diag) {   // mask: c00 (sub0 vs strip0), c11 (sub1 vs strip1)
            #pragma unroll
            for (int r = 0; r < 16; ++r) {
                int krow = (r & 3) + 8 * (r >> 2) + 4 * hi;
                if (krow > l31) { c00[r] = NEG_INF; c11[r] = NEG_INF; }
            }
        }
        // online softmax per strip (q = strip*32 + l31, lane-local + 1 shfl)
        float mx0 = NEG_INF, mx1 = NEG_INF;
        #pragma unroll
        for (int r = 0; r < 16; ++r) {
            mx0 = fmaxf(mx0, fmaxf(c00[r], c10[r]));
            mx1 = fmaxf(mx1, fmaxf(c01[r], c11[r]));
        }
        mx0 = fmaxf(mx0, __shfl_xor(mx0, 32));
        mx1 = fmaxf(mx1, __shfl_xor(mx1, 32));
        float mn0 = fmaxf(m0, mx0), mn1 = fmaxf(m1, mx1);
        float al0 = __expf(m0 - mn0), al1 = __expf(m1 - mn1);
        m0 = mn0; m1 = mn1;
        float s0 = 0.f, s1 = 0.f;
        #pragma unroll
        for (int r = 0; r < 16; ++r) {
            c00[r] = __expf(c00[r] - mn0); s0 += c00[r];
            c10[r] = __expf(c10[r] - mn0); s0 += c10[r];
            c01[r] = __expf(c01[r] - mn1); s1 += c01[r];
            c11[r] = __expf(c11[r] - mn1); s1 += c11[r];
        }
        s0 += __shfl_xor(s0, 32);
        s1 += __shfl_xor(s1, 32);
        l0 = l0 * al0 + s0;
        l1 = l1 * al1 + s1;
        #pragma unroll
        for (int r = 0; r < 16; ++r) {
            o00[r] *= al0; o10[r] *= al0;
            o01[r] *= al1; o11[r] *= al1;
        }
        // repack P per strip
        short8 p0h[4], p0l[4], p1h[4], p1l[4];
        pack_strip(c00, c10, p0h, p0l);
        pack_strip(c01, c11, p1h, p1l);

        __builtin_amdgcn_sched_barrier(0);   // keep V loads below the pack
        const size_t vt = (size_t)(b * 64 + kb) * 4096 + lane_off;
        short8 vh_[4], vl_[4];
        #pragma unroll
        for (int s = 0; s < 4; ++s) {
            vh_[s] = ld8(vthB + vt + s * 512);
            vl_[s] = ld8(vtlB + vt + s * 512);
        }
        __builtin_amdgcn_s_setprio(1);
        #pragma unroll
        for (int s = 0; s < 4; ++s) {
            o00 = MFMA(vh_[s], p0h[s], o00);
            o00 = MFMA(vh_[s], p0l[s], o00);
            o00 = MFMA(vl_[s], p0h[s], o00);
            o01 = MFMA(vh_[s], p1h[s], o01);
            o01 = MFMA(vh_[s], p1l[s], o01);
            o01 = MFMA(vl_[s], p1h[s], o01);
        }
        __builtin_amdgcn_s_setprio(0);
        #pragma unroll
        for (int s = 0; s < 4; ++s) {
            vh_[s] = ld8(vthB + vt + 2048 + s * 512);
            vl_[s] = ld8(vtlB + vt + 2048 + s * 512);
        }
        __builtin_amdgcn_s_setprio(1);
        #pragma unroll
        for (int s = 0; s < 4; ++s) {
            o10 = MFMA(vh_[s], p0h[s], o10);
            o10 = MFMA(vh_[s], p0l[s], o10);
            o10 = MFMA(vl_[s], p0h[s], o10);
            o11 = MFMA(vh_[s], p1h[s], o11);
            o11 = MFMA(vh_[s], p1l[s], o11);
            o11 = MFMA(vl_[s], p1h[s], o11);
        }
        __builtin_amdgcn_s_setprio(0);
    }
    const int pid = b * G + chunk;
    float* Op = Opart + (size_t)pid * 4096;   // [64 v][64 q]
    #pragma unroll
    for (int r = 0; r < 16; ++r) {
        int v0 = (r & 3) + 8 * (r >> 2) + 4 * hi;
        Op[v0 * 64 + l31]        = o00[r];
        Op[v0 * 64 + 32 + l31]   = o01[r];
        Op[(v0 + 32) * 64 + l31]      = o10[r];
        Op[(v0 + 32) * 64 + 32 + l31] = o11[r];
    }
    if (hi == 0) {
        mpart[pid * 64 + l31] = m0;       lpart[pid * 64 + l31] = l0;
        mpart[pid * 64 + 32 + l31] = m1;  lpart[pid * 64 + 32 + l31] = l1;
    }
}

// ---------------------------------------------------------------------------
// Merge: per (b,qs) combine its chunks, normalize, write out [b][t][64].
// ---------------------------------------------------------------------------
__global__ void merge_kernel(
    const float* __restrict__ Opart, const float* __restrict__ mpart,
    const float* __restrict__ lpart, float* __restrict__ out, int lc, int G)
{
    __shared__ float wgt[32][64];
    __shared__ float tr[64][65];
    const int bid = blockIdx.x;           // 0..255
    const int b = bid >> 6, qs = bid & 63;
    const int g = (qs + (1 << lc)) >> lc; // ceil((qs+1)/CH)
    const int base = b * G + cb64(qs, lc);
    const int tid = threadIdx.x;
    if (tid < 64) {
        float M = NEG_INF;
        for (int s = 0; s < g; ++s) M = fmaxf(M, mpart[(base + s) * 64 + tid]);
        float L = 0.f;
        for (int s = 0; s < g; ++s)
            L += lpart[(base + s) * 64 + tid] * __expf(mpart[(base + s) * 64 + tid] - M);
        float inv = 1.0f / L;
        for (int s = 0; s < g; ++s)
            wgt[s][tid] = __expf(mpart[(base + s) * 64 + tid] - M) * inv;
    }
    __syncthreads();
    float acc[16] = {};
    for (int s = 0; s < g; ++s) {
        const float* Op = Opart + (size_t)(base + s) * 4096;
        #pragma unroll
        for (int k = 0; k < 16; ++k) {
            int i = tid + k * 256;            // i = v*64 + q
            acc[k] += wgt[s][i & 63] * Op[i];
        }
    }
    #pragma unroll
    for (int k = 0; k < 16; ++k) {
        int i = tid + k * 256;
        tr[i & 63][i >> 6] = acc[k];          // tr[q][v]
    }
    __syncthreads();
    float* dst = out + ((size_t)b * 4096 + qs * 64) * 64;
    #pragma unroll
    for (int k = 0; k < 16; ++k) {
        int j = tid + k * 256;                // j = q*64 + v
        dst[j] = tr[j >> 6][j & 63];
    }
}

extern "C" void kernel_launch(void* const* d_in, const int* in_sizes, int n_in,
                              void* d_out, int out_size, void* d_ws, size_t ws_size,
                              hipStream_t stream) {
    const float* x   = (const float*)d_in[0];
    const float* Wq  = (const float*)d_in[1];
    const float* Wk  = (const float*)d_in[2];
    const float* Wv  = (const float*)d_in[3];
    const float* Wqs = (const float*)d_in[4];
    const float* Wks = (const float*)d_in[5];
    const float* Wvs = (const float*)d_in[6];
    float* out = (float*)d_out;

    char* ws = (char*)d_ws;
    const size_t MB = 1024 * 1024;
    u16* qh  = (u16*)(ws);
    u16* ql  = (u16*)(ws + 2 * MB);
    u16* kh  = (u16*)(ws + 4 * MB);
    u16* kl  = (u16*)(ws + 6 * MB);
    u16* vth = (u16*)(ws + 8 * MB);
    u16* vtl = (u16*)(ws + 10 * MB);
    u16* wbase = (u16*)(ws + 12 * MB);                 // 12 planes x 64KB
    float* mpart = (float*)(ws + 13 * MB);             // <= 1.1 MB
    float* lpart = (float*)(ws + 14 * MB + 512 * 1024);
    float* Opart = (float*)(ws + 16 * MB);

    int LC = 1, G = 1056;                                                       // CH=2, 66MB
    if (ws_size < 16 * MB + (size_t)4 * 1056 * 16384) { LC = 2; G = 544; }      // CH=4, 34MB
    if (ws_size < 16 * MB + (size_t)4 * 544  * 16384) { LC = 3; G = 288; }      // CH=8, 18MB

    convw_kernel<<<dim3(8, 6), 256, 0, stream>>>(Wq, Wk, Wv, Wqs, Wks, Wvs, wbase);
    proj_kernel<<<514, 128, 0, stream>>>(x, wbase, qh, ql, kh, kl, vth, vtl);
    flash_kernel<<<4 * G, 64, 0, stream>>>(qh, ql, kh, kl, vth, vtl,
                                           Opart, mpart, lpart, LC, G);
    merge_kernel<<<256, 256, 0, stream>>>(Opart, mpart, lpart, out, LC, G);
}

// Round 8
// 160.570 us; speedup vs baseline: 1.0846x; 1.0846x over previous
//
#include <hip/hip_runtime.h>
#include <hip/hip_bf16.h>

typedef unsigned short u16;
typedef __attribute__((ext_vector_type(8))) short short8;
typedef __attribute__((ext_vector_type(16))) float f32x16;

#define MFMA(A,B,C) __builtin_amdgcn_mfma_f32_32x32x16_bf16(A,B,C,0,0,0)
#define NEG_INF -1e30f
// q pre-scale: SCALE * log2(e) -> scores in log2 domain, P = 2^(s-m)
#define QSC (0.125f * 1.44269504f)

__device__ __forceinline__ float exp2_fast(float x) {
    float r;
    asm("v_exp_f32 %0, %1" : "=v"(r) : "v"(x));
    return r;
}
__device__ __forceinline__ unsigned cvtpk_bf16(float a, float b) {
    unsigned r;
    asm("v_cvt_pk_bf16_f32 %0, %1, %2" : "=v"(r) : "v"(a), "v"(b));
    return r;
}
__device__ __forceinline__ void permswap(unsigned &a, unsigned &b) {
    auto r = __builtin_amdgcn_permlane32_swap(a, b, false, false);
    a = r[0]; b = r[1];
}
union W4u { unsigned u[4]; short8 v; };
__device__ __forceinline__ short8 mk8(unsigned a, unsigned b, unsigned c, unsigned d) {
    W4u w; w.u[0] = a; w.u[1] = b; w.u[2] = c; w.u[3] = d; return w.v;
}
__device__ __forceinline__ void split_words(float p0, float p1, unsigned &wh, unsigned &wl) {
    wh = cvtpk_bf16(p0, p1);
    float h0 = __uint_as_float(wh << 16);
    float h1 = __uint_as_float(wh & 0xffff0000u);
    wl = cvtpk_bf16(p0 - h0, p1 - h1);
}
__device__ __forceinline__ void split_store(float v, u16* ph, u16* pl) {
    __hip_bfloat16 h = __float2bfloat16(v);
    float hf = __bfloat162float(h);
    __hip_bfloat16 l = __float2bfloat16(v - hf);
    *ph = *(u16*)&h;
    *pl = *(u16*)&l;
}
__device__ __forceinline__ void store_hi(float v, u16* ph) {
    __hip_bfloat16 h = __float2bfloat16(v);
    *ph = *(u16*)&h;
}
__device__ __forceinline__ short8 ld8(const u16* p) { return *(const short8*)p; }

// chunks (CH=1<<lc 64-key tiles each) in 64-row q-strips [0, qs) of one batch
__device__ __forceinline__ int cb64(int qs, int lc) {
    int u = qs >> lc, r = qs - (u << lc);
    return (((u * (u + 1)) >> 1) << lc) + r * (u + 1);
}

// fragment-linear index for Q/K: row grow (global across b*4096+t), col 0..63
__device__ __forceinline__ size_t qk_idx(int grow, int col) {
    return (size_t)(grow >> 5) * 2048 + (col >> 4) * 512 + (grow & 31) * 16
         + ((col >> 3) & 1) * 8 + (col & 7);
}

// pack one strip's P (c_sub0, c_sub1 f32x16) into 4 hi + 4 lo B-fragments
__device__ __forceinline__ void pack_strip(const f32x16 &ca, const f32x16 &cb,
                                           short8 *pbh, short8 *pbl) {
    unsigned wAh, wAl, wBh, wBl, wCh, wCl, wDh, wDl;
    split_words(ca[0], ca[1], wAh, wAl);   split_words(ca[2], ca[3], wBh, wBl);
    split_words(ca[4], ca[5], wCh, wCl);   split_words(ca[6], ca[7], wDh, wDl);
    permswap(wAh, wCh); permswap(wBh, wDh); permswap(wAl, wCl); permswap(wBl, wDl);
    pbh[0] = mk8(wAh, wBh, wCh, wDh); pbl[0] = mk8(wAl, wBl, wCl, wDl);
    split_words(ca[8], ca[9], wAh, wAl);   split_words(ca[10], ca[11], wBh, wBl);
    split_words(ca[12], ca[13], wCh, wCl); split_words(ca[14], ca[15], wDh, wDl);
    permswap(wAh, wCh); permswap(wBh, wDh); permswap(wAl, wCl); permswap(wBl, wDl);
    pbh[1] = mk8(wAh, wBh, wCh, wDh); pbl[1] = mk8(wAl, wBl, wCl, wDl);
    split_words(cb[0], cb[1], wAh, wAl);   split_words(cb[2], cb[3], wBh, wBl);
    split_words(cb[4], cb[5], wCh, wCl);   split_words(cb[6], cb[7], wDh, wDl);
    permswap(wAh, wCh); permswap(wBh, wDh); permswap(wAl, wCl); permswap(wBl, wDl);
    pbh[2] = mk8(wAh, wBh, wCh, wDh); pbl[2] = mk8(wAl, wBl, wCl, wDl);
    split_words(cb[8], cb[9], wAh, wAl);   split_words(cb[10], cb[11], wBh, wBl);
    split_words(cb[12], cb[13], wCh, wCl); split_words(cb[14], cb[15], wDh, wDl);
    permswap(wAh, wCh); permswap(wBh, wDh); permswap(wAl, wCl); permswap(wBl, wDl);
    pbh[3] = mk8(wAh, wBh, wCh, wDh); pbl[3] = mk8(wAl, wBl, wCl, wDl);
}

// ---------------------------------------------------------------------------
// Weights (fp32 [512][64]) -> fragment-linear hi/lo bf16 planes (both planes
// kept for generality; proj consumes hi+lo for the 3-term x@W).
// ---------------------------------------------------------------------------
__global__ void convw_kernel(
    const float* __restrict__ Wq, const float* __restrict__ Wk, const float* __restrict__ Wv,
    const float* __restrict__ Wqs, const float* __restrict__ Wks, const float* __restrict__ Wvs,
    u16* __restrict__ wbase)
{
    const int z = blockIdx.y;      // 0..5
    const int tile = blockIdx.x;   // 0..7 (64-d chunks)
    const float* W = (z == 0) ? Wq : (z == 1) ? Wk : (z == 2) ? Wv
                   : (z == 3) ? Wqs : (z == 4) ? Wks : Wvs;
    u16* oh = wbase + (size_t)z * 65536;
    u16* ol = oh + 32768;
    __shared__ float Xs[64][65];
    __shared__ u16 stg[8192];
    const int tid = threadIdx.x;
    const int d0 = tile * 64;
    #pragma unroll
    for (int k = 0; k < 16; ++k) {
        int idx = tid + k * 256;
        int d = idx >> 6, c = idx & 63;
        Xs[d][c] = W[(size_t)(d0 + d) * 64 + c];
    }
    __syncthreads();
    #pragma unroll
    for (int k = 0; k < 16; ++k) {
        int odx = tid + k * 256;
        int j = odx & 7, hi8 = (odx >> 3) & 1, r = (odx >> 4) & 63, sl = odx >> 10;
        split_store(Xs[sl * 16 + hi8 * 8 + j][r], &stg[odx], &stg[4096 + odx]);
    }
    __syncthreads();
    #pragma unroll
    for (int rep = 0; rep < 2; ++rep) {
        int i = (tid * 2 + rep) * 8;
        *(short8*)&oh[(size_t)tile * 4096 + i] = *(const short8*)&stg[i];
        *(short8*)&ol[(size_t)tile * 4096 + i] = *(const short8*)&stg[4096 + i];
    }
}

// ---------------------------------------------------------------------------
// QKV projection. 2-wave blocks (K-split), LDS cross-wave reduce, LDS staging,
// coalesced 16B stores. Emits: q hi+lo (pre-scaled by QSC), k hi, v hi.
// Blocks 0..511: mid weights; 512..513: the 64 edge rows with _s weights.
// ---------------------------------------------------------------------------
__global__ __launch_bounds__(128, 2) void proj_kernel(
    const float* __restrict__ x, const u16* __restrict__ wbase,
    u16* __restrict__ qh, u16* __restrict__ ql,
    u16* __restrict__ kh, u16* __restrict__ vth)
{
    __shared__ __align__(16) char smraw[24576];
    float (*red)[16][64] = (float (*)[16][64])smraw;   // [6][16][64]
    u16* stg = (u16*)smraw;                            // staging: 8192 u16 used

    const int bid = blockIdx.x;
    const bool edge = (bid >= 512);
    int sidx;
    if (!edge) { int xcd = bid & 7; sidx = (xcd >> 1) * 128 + (xcd & 1) * 64 + (bid >> 3); }
    else sidx = bid;
    const int w = threadIdx.x >> 6;
    const int lane = threadIdx.x & 63;
    const int l31 = lane & 31, hi = lane >> 5;

    const u16* wb = wbase + (edge ? (size_t)3 * 65536 : 0);
    const u16* wqh_ = wb;                 const u16* wql_ = wb + 32768;
    const u16* wkh_ = wb + 65536;         const u16* wkl_ = wb + 65536 + 32768;
    const u16* wvh_ = wb + 2 * 65536;     const u16* wvl_ = wb + 2 * 65536 + 32768;

    int growA;
    if (!edge) growA = sidx * 32 + l31;
    else {
        int e = sidx - 512, rb = l31 >> 4, i = l31 & 15;
        growA = (2 * e + rb) * 4096 + (i < 8 ? i : 4080 + i);
    }
    const float* xrow = x + (size_t)growA * 512;

    f32x16 aq[2] = {{}, {}}, ak[2] = {{}, {}}, av[2] = {{}, {}};
    const int s0 = w * 16;
    #pragma unroll 2
    for (int si = 0; si < 16; ++si) {
        const int s = s0 + si;
        const int d0 = s * 16 + 8 * hi;
        float4 xa = *(const float4*)(xrow + d0);
        float4 xb = *(const float4*)(xrow + d0 + 4);
        unsigned xh_[4], xl_[4];
        split_words(xa.x, xa.y, xh_[0], xl_[0]);
        split_words(xa.z, xa.w, xh_[1], xl_[1]);
        split_words(xb.x, xb.y, xh_[2], xl_[2]);
        split_words(xb.z, xb.w, xh_[3], xl_[3]);
        short8 xhf = mk8(xh_[0], xh_[1], xh_[2], xh_[3]);
        short8 xlf = mk8(xl_[0], xl_[1], xl_[2], xl_[3]);
        #pragma unroll
        for (int half = 0; half < 2; ++half) {
            size_t wof = (size_t)s * 1024 + (half * 32 + l31) * 16 + hi * 8;
            short8 qH = ld8(wqh_ + wof), qL = ld8(wql_ + wof);
            short8 kH = ld8(wkh_ + wof), kL = ld8(wkl_ + wof);
            short8 vH = ld8(wvh_ + wof), vL = ld8(wvl_ + wof);
            aq[half] = MFMA(xhf, qH, aq[half]);
            aq[half] = MFMA(xhf, qL, aq[half]);
            aq[half] = MFMA(xlf, qH, aq[half]);
            ak[half] = MFMA(xhf, kH, ak[half]);
            ak[half] = MFMA(xhf, kL, ak[half]);
            ak[half] = MFMA(xlf, kH, ak[half]);
            av[half] = MFMA(vH, xhf, av[half]);
            av[half] = MFMA(vL, xhf, av[half]);
            av[half] = MFMA(vH, xlf, av[half]);
        }
    }
    // publish partials: wave1 -> q,k; wave0 -> v
    if (w == 1) {
        #pragma unroll
        for (int h = 0; h < 2; ++h)
            #pragma unroll
            for (int r = 0; r < 16; ++r) {
                red[h][r][lane] = aq[h][r];
                red[2 + h][r][lane] = ak[h][r];
            }
    } else {
        #pragma unroll
        for (int h = 0; h < 2; ++h)
            #pragma unroll
            for (int r = 0; r < 16; ++r) red[4 + h][r][lane] = av[h][r];
    }
    __syncthreads();
    if (w == 0) {
        #pragma unroll
        for (int h = 0; h < 2; ++h)
            #pragma unroll
            for (int r = 0; r < 16; ++r) {
                aq[h][r] += red[h][r][lane];
                ak[h][r] += red[2 + h][r][lane];
            }
    } else {
        #pragma unroll
        for (int h = 0; h < 2; ++h)
            #pragma unroll
            for (int r = 0; r < 16; ++r) av[h][r] += red[4 + h][r][lane];
    }
    __syncthreads();   // red reads done; LDS now staging

    if (!edge) {
        // stage: q hi [0,2048), q lo [2048,4096), k hi [4096,6144), v hi [6144,8192)
        if (w == 0) {
            #pragma unroll
            for (int half = 0; half < 2; ++half)
                #pragma unroll
                for (int r = 0; r < 16; ++r) {
                    const int crow = (r & 3) + 8 * (r >> 2) + 4 * hi;
                    const int col = half * 32 + l31;
                    int loff = (col >> 4) * 512 + crow * 16 + ((col >> 3) & 1) * 8 + (col & 7);
                    split_store(aq[half][r] * QSC, &stg[loff], &stg[2048 + loff]);
                    store_hi(ak[half][r], &stg[4096 + loff]);
                }
        } else {
            #pragma unroll
            for (int half = 0; half < 2; ++half)
                #pragma unroll
                for (int r = 0; r < 16; ++r) {
                    const int crow = (r & 3) + 8 * (r >> 2) + 4 * hi;
                    int lv = half * 1024 + (l31 >> 4) * 512 + crow * 16
                           + ((l31 >> 3) & 1) * 8 + (l31 & 7);
                    store_hi(av[half][r], &stg[6144 + lv]);
                }
        }
        __syncthreads();
        // coalesced copy-out (both waves, 128 threads)
        const int t128 = threadIdx.x;
        const int sloc = sidx & 127;
        u16* qk0 = qh + (size_t)sidx * 2048;
        u16* qk1 = ql + (size_t)sidx * 2048;
        u16* qk2 = kh + (size_t)sidx * 2048;
        #pragma unroll
        for (int rep = 0; rep < 2; ++rep) {
            int i = (t128 * 2 + rep) * 8;            // 0..2040 step 8
            int crow_ = (i >> 4) & 31;
            int tin = sloc * 32 + crow_;
            if (tin >= 8 && tin < 4088) {
                *(short8*)&qk0[i] = *(const short8*)&stg[i];
                *(short8*)&qk1[i] = *(const short8*)&stg[2048 + i];
                *(short8*)&qk2[i] = *(const short8*)&stg[4096 + i];
            }
        }
        const size_t Vbase = (size_t)(sidx >> 1) * 4096;   // ttile = sidx>>1
        #pragma unroll
        for (int rep = 0; rep < 2; ++rep) {
            int i = (t128 * 2 + rep) * 8;
            int T = ((i >> 9) & 1) * 16 + ((i >> 3) & 1) * 8;
            int tbase = sloc * 32 + T;
            if (tbase >= 8 && tbase < 4088) {
                size_t go = Vbase + (size_t)(i >> 10) * 2048
                          + (((sidx & 1) << 1) + ((i >> 9) & 1)) * 512 + (i & 511);
                *(short8*)&vth[go] = *(const short8*)&stg[6144 + i];
            }
        }
    } else {
        // edge blocks: direct (scattered) stores — only 2 blocks
        const int bv = growA >> 12, tv = growA & 4095;
        if (w == 0) {
            #pragma unroll
            for (int half = 0; half < 2; ++half)
                #pragma unroll
                for (int r = 0; r < 16; ++r) {
                    const int crow = (r & 3) + 8 * (r >> 2) + 4 * hi;
                    const int col = half * 32 + l31;
                    int e = sidx - 512, rb = crow >> 4, i = crow & 15;
                    int growC = (2 * e + rb) * 4096 + (i < 8 ? i : 4080 + i);
                    size_t qo = qk_idx(growC, col);
                    split_store(aq[half][r] * QSC, qh + qo, ql + qo);
                    store_hi(ak[half][r], kh + qo);
                }
        } else {
            #pragma unroll
            for (int half = 0; half < 2; ++half)
                #pragma unroll
                for (int r = 0; r < 16; ++r) {
                    const int crow = (r & 3) + 8 * (r >> 2) + 4 * hi;
                    size_t vo = (size_t)(bv * 64 + (tv >> 6)) * 4096 + half * 2048
                              + ((tv & 63) >> 4) * 512 + crow * 16
                              + ((tv >> 3) & 1) * 8 + (tv & 7);
                    store_hi(av[half][r], vth + vo);
                }
        }
    }
}

// ---------------------------------------------------------------------------
// Flash attention: 64 q-rows/wave, K-hi single plane (Q keeps hi+lo),
// V-hi single plane (P keeps hi+lo). 2 load-waits per tile: all K in one
// batch; V issued right after QK so latency hides under softmax+pack.
// exp2-domain softmax (Q pre-scaled by log2e).
// ---------------------------------------------------------------------------
__global__ __launch_bounds__(64, 2) void flash_kernel(
    const u16* __restrict__ qhB, const u16* __restrict__ qlB,
    const u16* __restrict__ khB, const u16* __restrict__ vthB,
    float* __restrict__ Opart, float* __restrict__ mpart, float* __restrict__ lpart,
    int lc, int G)
{
    const int bid = blockIdx.x;
    const int xcd = bid & 7;
    const int b = xcd >> 1, par = xcd & 1;
    const int rr = bid >> 3;
    const int chunk = (G - 1) - (2 * rr + par);
    int qs = 0;
    for (int step = 32; step; step >>= 1) {
        int cand = qs + step;
        if (cand < 64 && cb64(cand, lc) <= chunk) qs = cand;
    }
    const int cloc = chunk - cb64(qs, lc);
    const int nt = qs + 1;
    const int klo = cloc << lc;
    const int lim = klo + (1 << lc);
    const int khi = (nt < lim) ? nt : lim;
    const int lane = threadIdx.x, l31 = lane & 31, hi = lane >> 5;
    const size_t lane_off = (size_t)(l31 * 16 + hi * 8);

    const size_t qb0 = (size_t)(b * 128 + qs * 2) * 2048 + lane_off;
    short8 q0h[4], q0l[4], q1h[4], q1l[4];
    #pragma unroll
    for (int s = 0; s < 4; ++s) {
        q0h[s] = ld8(qhB + qb0 + s * 512);
        q0l[s] = ld8(qlB + qb0 + s * 512);
        q1h[s] = ld8(qhB + qb0 + 2048 + s * 512);
        q1l[s] = ld8(qlB + qb0 + 2048 + s * 512);
    }

    f32x16 o00 = {}, o01 = {}, o10 = {}, o11 = {};
    float m0 = NEG_INF, l0 = 0.f, m1 = NEG_INF, l1 = 0.f;

    for (int kb = klo; kb < khi; ++kb) {
        const bool diag = (kb == qs);
        const size_t kt = (size_t)(b * 128 + kb * 2) * 2048 + lane_off;
        short8 kf0[4], kf1[4];
        #pragma unroll
        for (int s = 0; s < 4; ++s) {
            kf0[s] = ld8(khB + kt + s * 512);
            kf1[s] = ld8(khB + kt + 2048 + s * 512);
        }
        f32x16 c00 = {}, c01 = {}, c11 = {};
        f32x16 c10;
        #pragma unroll
        for (int r = 0; r < 16; ++r) c10[r] = diag ? NEG_INF : 0.f;

        __builtin_amdgcn_s_setprio(1);
        #pragma unroll
        for (int s = 0; s < 4; ++s) {
            c00 = MFMA(kf0[s], q0h[s], c00);
            c00 = MFMA(kf0[s], q0l[s], c00);
            c01 = MFMA(kf0[s], q1h[s], c01);
            c01 = MFMA(kf0[s], q1l[s], c01);
        }
        if (!diag) {
            #pragma unroll
            for (int s = 0; s < 4; ++s) {
                c10 = MFMA(kf1[s], q0h[s], c10);
                c10 = MFMA(kf1[s], q0l[s], c10);
            }
        }
        #pragma unroll
        for (int s = 0; s < 4; ++s) {
            c11 = MFMA(kf1[s], q1h[s], c11);
            c11 = MFMA(kf1[s], q1l[s], c11);
        }
        __builtin_amdgcn_s_setprio(0);

        // V loads issued now; latency hides under softmax + pack
        const size_t vt = (size_t)(b * 64 + kb) * 4096 + lane_off;
        short8 v0[4], v1[4];
        #pragma unroll
        for (int s = 0; s < 4; ++s) {
            v0[s] = ld8(vthB + vt + s * 512);
            v1[s] = ld8(vthB + vt + 2048 + s * 512);
        }

        if (diag) {
            #pragma unroll
            for (int r = 0; r < 16; ++r) {
                int krow = (r & 3) + 8 * (r >> 2) + 4 * hi;
                if (krow > l31) { c00[r] = NEG_INF; c11[r] = NEG_INF; }
            }
        }
        // online softmax per strip, log2 domain
        float mx0 = NEG_INF, mx1 = NEG_INF;
        #pragma unroll
        for (int r = 0; r < 16; ++r) {
            mx0 = fmaxf(mx0, fmaxf(c00[r], c10[r]));
            mx1 = fmaxf(mx1, fmaxf(c01[r], c11[r]));
        }
        mx0 = fmaxf(mx0, __shfl_xor(mx0, 32));
        mx1 = fmaxf(mx1, __shfl_xor(mx1, 32));
        float mn0 = fmaxf(m0, mx0), mn1 = fmaxf(m1, mx1);
        float al0 = exp2_fast(m0 - mn0), al1 = exp2_fast(m1 - mn1);
        m0 = mn0; m1 = mn1;
        float s0 = 0.f, s1 = 0.f;
        #pragma unroll
        for (int r = 0; r < 16; ++r) {
            c00[r] = exp2_fast(c00[r] - mn0); s0 += c00[r];
            c10[r] = exp2_fast(c10[r] - mn0); s0 += c10[r];
            c01[r] = exp2_fast(c01[r] - mn1); s1 += c01[r];
            c11[r] = exp2_fast(c11[r] - mn1); s1 += c11[r];
        }
        s0 += __shfl_xor(s0, 32);
        s1 += __shfl_xor(s1, 32);
        l0 = l0 * al0 + s0;
        l1 = l1 * al1 + s1;
        #pragma unroll
        for (int r = 0; r < 16; ++r) {
            o00[r] *= al0; o10[r] *= al0;
            o01[r] *= al1; o11[r] *= al1;
        }
        short8 p0h[4], p0l[4], p1h[4], p1l[4];
        pack_strip(c00, c10, p0h, p0l);
        pack_strip(c01, c11, p1h, p1l);

        __builtin_amdgcn_s_setprio(1);
        #pragma unroll
        for (int s = 0; s < 4; ++s) {
            o00 = MFMA(v0[s], p0h[s], o00);
            o00 = MFMA(v0[s], p0l[s], o00);
            o01 = MFMA(v0[s], p1h[s], o01);
            o01 = MFMA(v0[s], p1l[s], o01);
            o10 = MFMA(v1[s], p0h[s], o10);
            o10 = MFMA(v1[s], p0l[s], o10);
            o11 = MFMA(v1[s], p1h[s], o11);
            o11 = MFMA(v1[s], p1l[s], o11);
        }
        __builtin_amdgcn_s_setprio(0);
    }
    const int pid = b * G + chunk;
    float* Op = Opart + (size_t)pid * 4096;   // [64 v][64 q]
    #pragma unroll
    for (int r = 0; r < 16; ++r) {
        int v0i = (r & 3) + 8 * (r >> 2) + 4 * hi;
        Op[v0i * 64 + l31]             = o00[r];
        Op[v0i * 64 + 32 + l31]        = o01[r];
        Op[(v0i + 32) * 64 + l31]      = o10[r];
        Op[(v0i + 32) * 64 + 32 + l31] = o11[r];
    }
    if (hi == 0) {
        mpart[pid * 64 + l31] = m0;       lpart[pid * 64 + l31] = l0;
        mpart[pid * 64 + 32 + l31] = m1;  lpart[pid * 64 + 32 + l31] = l1;
    }
}

// ---------------------------------------------------------------------------
// Merge: per (b,qs) combine chunks (log2-domain m), normalize, write out.
// ---------------------------------------------------------------------------
__global__ void merge_kernel(
    const float* __restrict__ Opart, const float* __restrict__ mpart,
    const float* __restrict__ lpart, float* __restrict__ out, int lc, int G)
{
    __shared__ float wgt[32][64];
    __shared__ float tr[64][65];
    const int bid = blockIdx.x;           // 0..255
    const int b = bid >> 6, qs = bid & 63;
    const int g = (qs + (1 << lc)) >> lc; // ceil((qs+1)/CH)
    const int base = b * G + cb64(qs, lc);
    const int tid = threadIdx.x;
    if (tid < 64) {
        float M = NEG_INF;
        for (int s = 0; s < g; ++s) M = fmaxf(M, mpart[(base + s) * 64 + tid]);
        float L = 0.f;
        for (int s = 0; s < g; ++s)
            L += lpart[(base + s) * 64 + tid] * exp2_fast(mpart[(base + s) * 64 + tid] - M);
        float inv = 1.0f / L;
        for (int s = 0; s < g; ++s)
            wgt[s][tid] = exp2_fast(mpart[(base + s) * 64 + tid] - M) * inv;
    }
    __syncthreads();
    float acc[16] = {};
    for (int s = 0; s < g; ++s) {
        const float* Op = Opart + (size_t)(base + s) * 4096;
        #pragma unroll
        for (int k = 0; k < 16; ++k) {
            int i = tid + k * 256;            // i = v*64 + q
            acc[k] += wgt[s][i & 63] * Op[i];
        }
    }
    #pragma unroll
    for (int k = 0; k < 16; ++k) {
        int i = tid + k * 256;
        tr[i & 63][i >> 6] = acc[k];          // tr[q][v]
    }
    __syncthreads();
    float* dst = out + ((size_t)b * 4096 + qs * 64) * 64;
    #pragma unroll
    for (int k = 0; k < 16; ++k) {
        int j = tid + k * 256;                // j = q*64 + v
        dst[j] = tr[j >> 6][j & 63];
    }
}

extern "C" void kernel_launch(void* const* d_in, const int* in_sizes, int n_in,
                              void* d_out, int out_size, void* d_ws, size_t ws_size,
                              hipStream_t stream) {
    const float* x   = (const float*)d_in[0];
    const float* Wq  = (const float*)d_in[1];
    const float* Wk  = (const float*)d_in[2];
    const float* Wv  = (const float*)d_in[3];
    const float* Wqs = (const float*)d_in[4];
    const float* Wks = (const float*)d_in[5];
    const float* Wvs = (const float*)d_in[6];
    float* out = (float*)d_out;

    char* ws = (char*)d_ws;
    const size_t MB = 1024 * 1024;
    u16* qh  = (u16*)(ws);
    u16* ql  = (u16*)(ws + 2 * MB);
    u16* kh  = (u16*)(ws + 4 * MB);
    u16* vth = (u16*)(ws + 6 * MB);
    u16* wbase = (u16*)(ws + 8 * MB);                  // 12 planes x 64KB
    float* mpart = (float*)(ws + 9 * MB);              // <= 557KB
    float* lpart = (float*)(ws + 10 * MB);
    float* Opart = (float*)(ws + 11 * MB);

    int LC = 2, G = 544;                                                        // CH=4, 34MB
    if (ws_size < 11 * MB + (size_t)4 * 544 * 16384) { LC = 3; G = 288; }       // CH=8, 18MB
    if (ws_size < 11 * MB + (size_t)4 * 288 * 16384) { LC = 4; G = 160; }       // CH=16, 10MB

    convw_kernel<<<dim3(8, 6), 256, 0, stream>>>(Wq, Wk, Wv, Wqs, Wks, Wvs, wbase);
    proj_kernel<<<514, 128, 0, stream>>>(x, wbase, qh, ql, kh, vth);
    flash_kernel<<<4 * G, 64, 0, stream>>>(qh, ql, kh, vth,
                                           Opart, mpart, lpart, LC, G);
    merge_kernel<<<256, 256, 0, stream>>>(Opart, mpart, lpart, out, LC, G);
}